// Round 18
// baseline (61.230 us; speedup 1.0000x reference)
//
#include <hip/hip_runtime.h>

// crop_and_resize (RoIAlign-style bilinear), fp32, NHWC.
// feats: (8, 64, 64, 256) fp32 = 4 MiB/image; boxes: (4000,4); box_ind: (4000,)
// out:   (4000, 7, 7, 256) fp32
//
// R16: single-launch. R15 (best, 69.7us) = bucket kernel (~5us launch+run)
// + crop (~65us, pinned across 8 structural variants; measured anatomy:
// nt-stores 39us + L2 gathers 16us + ~10us non-overlap). This round folds
// the bucket into the crop kernel as a 4-wave-parallel stable in-LDS bucket
// (~1us/block, fully parallel) and drops the separate launch.
// Crop structure identical to R15: XCD partition, lane-parallel geometry,
// saddr gathers, nt stores, grid 6144.

#define H 64
#define W 64
#define C 256
#define CROP_HW 49  // 7*7
#define NIMG 8
#define G 8         // cells per wave-group (lane-parallel geometry)
#define MAXB 4096   // in-LDS order capacity

typedef float f32x4 __attribute__((ext_vector_type(4)));

// ---- per-cell geometry (pixel indices, no lane folded in) ------------------
struct Cell {
    int p00, p01, p10, p11;   // pixel index y*W+x within image
    float wx, wy;
    bool valid;
    int oidx;                 // float4-granular output index (without lane)
};

__device__ __forceinline__ Cell cell_info(
    int c, const int* order, const f32x4* __restrict__ boxes4)
{
    Cell k;
    const int bi = c / CROP_HW;
    const int r  = c - bi * CROP_HW;
    const int iy = r / 7;
    const int ix = r - iy * 7;
    const int b  = order[bi];

    const f32x4 bx = boxes4[b];   // {y1, x1, y2, x2}

    // reference order: step = (hi-lo)*(extent-1)/(n-1); s = lo*(extent-1)+i*step
    const float stepy = (bx.z - bx.x) * 63.0f / 6.0f;
    const float stepx = (bx.w - bx.y) * 63.0f / 6.0f;
    const float ys = bx.x * 63.0f + (float)iy * stepy;
    const float xs = bx.y * 63.0f + (float)ix * stepx;

    const float y0f = floorf(ys);
    const float x0f = floorf(xs);
    k.wy = ys - y0f;
    k.wx = xs - x0f;

    const int y0 = min(max((int)y0f, 0), H - 1);
    const int y1 = min(y0 + 1, H - 1);
    const int x0 = min(max((int)x0f, 0), W - 1);
    const int x1 = min(x0 + 1, W - 1);

    k.valid = (ys >= 0.0f) && (ys <= (float)(H - 1)) &&
              (xs >= 0.0f) && (xs <= (float)(W - 1));

    k.p00 = y0 * W + x0;
    k.p01 = y0 * W + x1;
    k.p10 = y1 * W + x0;
    k.p11 = y1 * W + x1;

    k.oidx = (b * CROP_HW + r) * (C / 4);
    return k;
}

// ---- 4-wave-parallel stable in-LDS bucket ----------------------------------
// wave w scans box range [w*Q, min(n,(w+1)*Q)); within a 256-box chunk, lane
// l holds indices base+l, base+64+l, base+128+l, base+192+l (4 batched
// loads), then 4 ballot-compact rounds in index order -> stable.
__device__ __forceinline__ int block_bucket4(
    const int* __restrict__ box_ind, int nbox, int img, int lane, int wv,
    int* s_order, int* s_cnt)
{
    const int Q  = (nbox + 3) >> 2;
    const int lo = wv * Q;
    const int hi = min(nbox, lo + Q);

    // pass 1: count matches in my range
    int cnt = 0;
    for (int base = lo; base < hi; base += 256) {
        int a0 = (base       + lane < hi) ? box_ind[base       + lane] : -1;
        int a1 = (base + 64  + lane < hi) ? box_ind[base + 64  + lane] : -1;
        int a2 = (base + 128 + lane < hi) ? box_ind[base + 128 + lane] : -1;
        int a3 = (base + 192 + lane < hi) ? box_ind[base + 192 + lane] : -1;
        cnt += (a0 == img) + (a1 == img) + (a2 == img) + (a3 == img);
    }
    for (int off = 32; off; off >>= 1) cnt += __shfl_down(cnt, off);
    if (lane == 0) s_cnt[wv] = cnt;
    __syncthreads();

    int pos = 0;
    for (int u = 0; u < wv; ++u) pos += s_cnt[u];
    const int nb = s_cnt[0] + s_cnt[1] + s_cnt[2] + s_cnt[3];

    // pass 2: stable ballot compaction (index order within and across rounds)
    for (int base = lo; base < hi; base += 256) {
        int a0 = (base       + lane < hi) ? box_ind[base       + lane] : -1;
        int a1 = (base + 64  + lane < hi) ? box_ind[base + 64  + lane] : -1;
        int a2 = (base + 128 + lane < hi) ? box_ind[base + 128 + lane] : -1;
        int a3 = (base + 192 + lane < hi) ? box_ind[base + 192 + lane] : -1;

        #define ROUND(A, OFF) { \
            const bool m = (A == img); \
            const unsigned long long mask = __ballot(m); \
            const int below = __popcll(mask & ((1ULL << lane) - 1ULL)); \
            if (m) s_order[pos + below] = base + OFF + lane; \
            pos += __popcll(mask); }
        ROUND(a0, 0) ROUND(a1, 64) ROUND(a2, 128) ROUND(a3, 192)
        #undef ROUND
    }
    __syncthreads();
    return nb;
}

// ---- crop kernel: XCD-partitioned, lane-parallel geometry, in-LDS bucket ---
__global__ __launch_bounds__(256) void crop_resize_xcd(
    const float* __restrict__ feats,
    const float* __restrict__ boxes,
    const int*   __restrict__ box_ind,
    float*       __restrict__ out,
    int nbox)
{
    const int img  = blockIdx.x & 7;     // block->XCD round-robin heuristic
    const int slot = blockIdx.x >> 3;
    const int lane = threadIdx.x & 63;
    const int wv   = threadIdx.x >> 6;   // 0..3

    __shared__ int s_order[MAXB];
    __shared__ int s_cnt[4];
    const int nb = block_bucket4(box_ind, nbox, img, lane, wv, s_order, s_cnt);

    const int ncells  = nb * CROP_HW;
    const int ngroups = (ncells + G - 1) / G;
    const int wave_local = slot * 4 + wv;
    const int stride     = (gridDim.x >> 3) * 4;

    const f32x4* __restrict__ f4 = reinterpret_cast<const f32x4*>(feats)
                                   + (size_t)img * (H * W * (C / 4));
    const f32x4* __restrict__ boxes4 = reinterpret_cast<const f32x4*>(boxes);
    f32x4* __restrict__ o4 = reinterpret_cast<f32x4*>(out);

    for (int gi = wave_local; gi < ngroups; gi += stride) {
        const int cbase = gi * G;
        const int nval  = min(G, ncells - cbase);   // wave-uniform

        // phase A: lane computes geometry for cell cbase + (lane & 7)
        int c = cbase + (lane & (G - 1));
        if (c > ncells - 1) c = ncells - 1;
        const Cell k = cell_info(c, s_order, boxes4);
        const unsigned long long vmask = __ballot(k.valid);

        // phase B: per cell j, broadcast params to SGPRs, gather, lerp, store.
        #pragma unroll
        for (int j = 0; j < G; ++j) {
            if (j >= nval) break;                      // wave-uniform
            const int   s00 = __builtin_amdgcn_readlane(k.p00, j);
            const int   s01 = __builtin_amdgcn_readlane(k.p01, j);
            const int   s10 = __builtin_amdgcn_readlane(k.p10, j);
            const int   s11 = __builtin_amdgcn_readlane(k.p11, j);
            const float swx = __uint_as_float(
                __builtin_amdgcn_readlane(__float_as_uint(k.wx), j));
            const float swy = __uint_as_float(
                __builtin_amdgcn_readlane(__float_as_uint(k.wy), j));
            const int   sox = __builtin_amdgcn_readlane(k.oidx, j);
            const bool  sval = (vmask >> j) & 1ULL;    // wave-uniform

            // wave-uniform pixel base + lane*16B: saddr-form loads
            const f32x4 v00 = f4[s00 * (C / 4) + lane];
            const f32x4 v01 = f4[s01 * (C / 4) + lane];
            const f32x4 v10 = f4[s10 * (C / 4) + lane];
            const f32x4 v11 = f4[s11 * (C / 4) + lane];

            // 4-weight bilinear (16 FMA): weights sum to 1
            const float w11 = swx * swy;
            const float w01 = swx - w11;       // wx*(1-wy)
            const float w10 = swy - w11;       // (1-wx)*wy
            const float w00 = 1.0f - swx - swy + w11;

            f32x4 res = v00 * w00;
            res += v01 * w01;
            res += v10 * w10;
            res += v11 * w11;
            if (!sval) res = (f32x4)0.0f;      // wave-uniform

            __builtin_nontemporal_store(res, &o4[(size_t)sox + lane]);
        }
    }
}

// ---- fallback for nbox > MAXB: two-kernel path (never taken here) ----------
__global__ __launch_bounds__(512) void bucket_kernel(
    const int* __restrict__ box_ind, int* __restrict__ order,
    int* __restrict__ offsets, int n)
{
    const int wave = threadIdx.x >> 6;
    const int lane = threadIdx.x & 63;
    __shared__ int counts[NIMG];
    int cnt = 0;
    for (int i = lane; i < n; i += 64) cnt += (box_ind[i] == wave);
    for (int off = 32; off; off >>= 1) cnt += __shfl_down(cnt, off);
    if (lane == 0) counts[wave] = cnt;
    __syncthreads();
    int start = 0;
    for (int i = 0; i < wave; ++i) start += counts[i];
    if (threadIdx.x == 0) {
        int acc = 0;
        for (int i = 0; i < NIMG; ++i) { offsets[i] = acc; acc += counts[i]; }
        offsets[NIMG] = acc;
    }
    int pos = start;
    for (int base = 0; base < n; base += 64) {
        const int i = base + lane;
        const bool m = (i < n) && (box_ind[i] == wave);
        const unsigned long long mask = __ballot(m);
        const int below = __popcll(mask & ((1ULL << lane) - 1ULL));
        if (m) order[pos + below] = i;
        pos += __popcll(mask);
    }
}

__global__ __launch_bounds__(256) void crop_global_order(
    const float* __restrict__ feats,
    const float* __restrict__ boxes,
    const int*   __restrict__ order,
    const int*   __restrict__ offsets,
    float*       __restrict__ out)
{
    const int img  = blockIdx.x & 7;
    const int slot = blockIdx.x >> 3;
    const int lane = threadIdx.x & 63;
    const int wv   = threadIdx.x >> 6;
    const int start   = offsets[img];
    const int nb      = offsets[img + 1] - start;
    const int ncells  = nb * CROP_HW;
    const int ngroups = (ncells + G - 1) / G;
    const int wave_local = slot * 4 + wv;
    const int stride     = (gridDim.x >> 3) * 4;
    const f32x4* __restrict__ f4 = reinterpret_cast<const f32x4*>(feats)
                                   + (size_t)img * (H * W * (C / 4));
    const f32x4* __restrict__ boxes4 = reinterpret_cast<const f32x4*>(boxes);
    f32x4* __restrict__ o4 = reinterpret_cast<f32x4*>(out);

    for (int gi = wave_local; gi < ngroups; gi += stride) {
        const int cbase = gi * G;
        const int nval  = min(G, ncells - cbase);
        int c = cbase + (lane & (G - 1));
        if (c > ncells - 1) c = ncells - 1;
        const Cell k = cell_info(c, order + start, boxes4);
        const unsigned long long vmask = __ballot(k.valid);
        #pragma unroll
        for (int j = 0; j < G; ++j) {
            if (j >= nval) break;
            const int   s00 = __builtin_amdgcn_readlane(k.p00, j);
            const int   s01 = __builtin_amdgcn_readlane(k.p01, j);
            const int   s10 = __builtin_amdgcn_readlane(k.p10, j);
            const int   s11 = __builtin_amdgcn_readlane(k.p11, j);
            const float swx = __uint_as_float(
                __builtin_amdgcn_readlane(__float_as_uint(k.wx), j));
            const float swy = __uint_as_float(
                __builtin_amdgcn_readlane(__float_as_uint(k.wy), j));
            const int   sox = __builtin_amdgcn_readlane(k.oidx, j);
            const bool  sval = (vmask >> j) & 1ULL;
            const f32x4 v00 = f4[s00 * (C / 4) + lane];
            const f32x4 v01 = f4[s01 * (C / 4) + lane];
            const f32x4 v10 = f4[s10 * (C / 4) + lane];
            const f32x4 v11 = f4[s11 * (C / 4) + lane];
            const float w11 = swx * swy;
            const float w01 = swx - w11;
            const float w10 = swy - w11;
            const float w00 = 1.0f - swx - swy + w11;
            f32x4 res = v00 * w00;
            res += v01 * w01;
            res += v10 * w10;
            res += v11 * w11;
            if (!sval) res = (f32x4)0.0f;
            __builtin_nontemporal_store(res, &o4[(size_t)sox + lane]);
        }
    }
}

extern "C" void kernel_launch(void* const* d_in, const int* in_sizes, int n_in,
                              void* d_out, int out_size, void* d_ws, size_t ws_size,
                              hipStream_t stream) {
    const float* feats   = (const float*)d_in[0];
    const float* boxes   = (const float*)d_in[1];
    const int*   box_ind = (const int*)d_in[2];
    float*       out     = (float*)d_out;

    const int n_boxes = in_sizes[1] / 4;

    if (n_boxes <= MAXB) {
        // single launch: in-LDS bucket + crop. 6144 blocks (768/image).
        crop_resize_xcd<<<6144, 256, 0, stream>>>(feats, boxes, box_ind, out,
                                                  n_boxes);
    } else {
        int* order   = (int*)d_ws;
        int* offsets = order + n_boxes;
        bucket_kernel<<<1, 512, 0, stream>>>(box_ind, order, offsets, n_boxes);
        crop_global_order<<<6144, 256, 0, stream>>>(feats, boxes, order,
                                                    offsets, out);
    }
}

// Round 19
// 60.657 us; speedup vs baseline: 1.0094x; 1.0094x over previous
//
#include <hip/hip_runtime.h>

// crop_and_resize (RoIAlign-style bilinear), fp32, NHWC.
// feats: (8, 64, 64, 256) fp32 = 4 MiB/image; boxes: (4000,4); box_ind: (4000,)
// out:   (4000, 7, 7, 256) fp32
//
// R16: single-launch. R15 (best, 69.7us) = bucket kernel (~5us launch+run)
// + crop (~65us, pinned across 8 structural variants; measured anatomy:
// nt-stores 39us + L2 gathers 16us + ~10us non-overlap). This round folds
// the bucket into the crop kernel as a 4-wave-parallel stable in-LDS bucket
// (~1us/block, fully parallel) and drops the separate launch.
// Crop structure identical to R15: XCD partition, lane-parallel geometry,
// saddr gathers, nt stores, grid 6144.

#define H 64
#define W 64
#define C 256
#define CROP_HW 49  // 7*7
#define NIMG 8
#define G 8         // cells per wave-group (lane-parallel geometry)
#define MAXB 4096   // in-LDS order capacity

typedef float f32x4 __attribute__((ext_vector_type(4)));

// ---- per-cell geometry (pixel indices, no lane folded in) ------------------
struct Cell {
    int p00, p01, p10, p11;   // pixel index y*W+x within image
    float wx, wy;
    bool valid;
    int oidx;                 // float4-granular output index (without lane)
};

__device__ __forceinline__ Cell cell_info(
    int c, const int* order, const f32x4* __restrict__ boxes4)
{
    Cell k;
    const int bi = c / CROP_HW;
    const int r  = c - bi * CROP_HW;
    const int iy = r / 7;
    const int ix = r - iy * 7;
    const int b  = order[bi];

    const f32x4 bx = boxes4[b];   // {y1, x1, y2, x2}

    // reference order: step = (hi-lo)*(extent-1)/(n-1); s = lo*(extent-1)+i*step
    const float stepy = (bx.z - bx.x) * 63.0f / 6.0f;
    const float stepx = (bx.w - bx.y) * 63.0f / 6.0f;
    const float ys = bx.x * 63.0f + (float)iy * stepy;
    const float xs = bx.y * 63.0f + (float)ix * stepx;

    const float y0f = floorf(ys);
    const float x0f = floorf(xs);
    k.wy = ys - y0f;
    k.wx = xs - x0f;

    const int y0 = min(max((int)y0f, 0), H - 1);
    const int y1 = min(y0 + 1, H - 1);
    const int x0 = min(max((int)x0f, 0), W - 1);
    const int x1 = min(x0 + 1, W - 1);

    k.valid = (ys >= 0.0f) && (ys <= (float)(H - 1)) &&
              (xs >= 0.0f) && (xs <= (float)(W - 1));

    k.p00 = y0 * W + x0;
    k.p01 = y0 * W + x1;
    k.p10 = y1 * W + x0;
    k.p11 = y1 * W + x1;

    k.oidx = (b * CROP_HW + r) * (C / 4);
    return k;
}

// ---- 4-wave-parallel stable in-LDS bucket ----------------------------------
// wave w scans box range [w*Q, min(n,(w+1)*Q)); within a 256-box chunk, lane
// l holds indices base+l, base+64+l, base+128+l, base+192+l (4 batched
// loads), then 4 ballot-compact rounds in index order -> stable.
__device__ __forceinline__ int block_bucket4(
    const int* __restrict__ box_ind, int nbox, int img, int lane, int wv,
    int* s_order, int* s_cnt)
{
    const int Q  = (nbox + 3) >> 2;
    const int lo = wv * Q;
    const int hi = min(nbox, lo + Q);

    // pass 1: count matches in my range
    int cnt = 0;
    for (int base = lo; base < hi; base += 256) {
        int a0 = (base       + lane < hi) ? box_ind[base       + lane] : -1;
        int a1 = (base + 64  + lane < hi) ? box_ind[base + 64  + lane] : -1;
        int a2 = (base + 128 + lane < hi) ? box_ind[base + 128 + lane] : -1;
        int a3 = (base + 192 + lane < hi) ? box_ind[base + 192 + lane] : -1;
        cnt += (a0 == img) + (a1 == img) + (a2 == img) + (a3 == img);
    }
    for (int off = 32; off; off >>= 1) cnt += __shfl_down(cnt, off);
    if (lane == 0) s_cnt[wv] = cnt;
    __syncthreads();

    int pos = 0;
    for (int u = 0; u < wv; ++u) pos += s_cnt[u];
    const int nb = s_cnt[0] + s_cnt[1] + s_cnt[2] + s_cnt[3];

    // pass 2: stable ballot compaction (index order within and across rounds)
    for (int base = lo; base < hi; base += 256) {
        int a0 = (base       + lane < hi) ? box_ind[base       + lane] : -1;
        int a1 = (base + 64  + lane < hi) ? box_ind[base + 64  + lane] : -1;
        int a2 = (base + 128 + lane < hi) ? box_ind[base + 128 + lane] : -1;
        int a3 = (base + 192 + lane < hi) ? box_ind[base + 192 + lane] : -1;

        #define ROUND(A, OFF) { \
            const bool m = (A == img); \
            const unsigned long long mask = __ballot(m); \
            const int below = __popcll(mask & ((1ULL << lane) - 1ULL)); \
            if (m) s_order[pos + below] = base + OFF + lane; \
            pos += __popcll(mask); }
        ROUND(a0, 0) ROUND(a1, 64) ROUND(a2, 128) ROUND(a3, 192)
        #undef ROUND
    }
    __syncthreads();
    return nb;
}

// ---- crop kernel: XCD-partitioned, lane-parallel geometry, in-LDS bucket ---
__global__ __launch_bounds__(256) void crop_resize_xcd(
    const float* __restrict__ feats,
    const float* __restrict__ boxes,
    const int*   __restrict__ box_ind,
    float*       __restrict__ out,
    int nbox)
{
    const int img  = blockIdx.x & 7;     // block->XCD round-robin heuristic
    const int slot = blockIdx.x >> 3;
    const int lane = threadIdx.x & 63;
    const int wv   = threadIdx.x >> 6;   // 0..3

    __shared__ int s_order[MAXB];
    __shared__ int s_cnt[4];
    const int nb = block_bucket4(box_ind, nbox, img, lane, wv, s_order, s_cnt);

    const int ncells  = nb * CROP_HW;
    const int ngroups = (ncells + G - 1) / G;
    const int wave_local = slot * 4 + wv;
    const int stride     = (gridDim.x >> 3) * 4;

    const f32x4* __restrict__ f4 = reinterpret_cast<const f32x4*>(feats)
                                   + (size_t)img * (H * W * (C / 4));
    const f32x4* __restrict__ boxes4 = reinterpret_cast<const f32x4*>(boxes);
    f32x4* __restrict__ o4 = reinterpret_cast<f32x4*>(out);

    for (int gi = wave_local; gi < ngroups; gi += stride) {
        const int cbase = gi * G;
        const int nval  = min(G, ncells - cbase);   // wave-uniform

        // phase A: lane computes geometry for cell cbase + (lane & 7)
        int c = cbase + (lane & (G - 1));
        if (c > ncells - 1) c = ncells - 1;
        const Cell k = cell_info(c, s_order, boxes4);
        const unsigned long long vmask = __ballot(k.valid);

        // phase B: per cell j, broadcast params to SGPRs, gather, lerp, store.
        #pragma unroll
        for (int j = 0; j < G; ++j) {
            if (j >= nval) break;                      // wave-uniform
            const int   s00 = __builtin_amdgcn_readlane(k.p00, j);
            const int   s01 = __builtin_amdgcn_readlane(k.p01, j);
            const int   s10 = __builtin_amdgcn_readlane(k.p10, j);
            const int   s11 = __builtin_amdgcn_readlane(k.p11, j);
            const float swx = __uint_as_float(
                __builtin_amdgcn_readlane(__float_as_uint(k.wx), j));
            const float swy = __uint_as_float(
                __builtin_amdgcn_readlane(__float_as_uint(k.wy), j));
            const int   sox = __builtin_amdgcn_readlane(k.oidx, j);
            const bool  sval = (vmask >> j) & 1ULL;    // wave-uniform

            // wave-uniform pixel base + lane*16B: saddr-form loads
            const f32x4 v00 = f4[s00 * (C / 4) + lane];
            const f32x4 v01 = f4[s01 * (C / 4) + lane];
            const f32x4 v10 = f4[s10 * (C / 4) + lane];
            const f32x4 v11 = f4[s11 * (C / 4) + lane];

            // 4-weight bilinear (16 FMA): weights sum to 1
            const float w11 = swx * swy;
            const float w01 = swx - w11;       // wx*(1-wy)
            const float w10 = swy - w11;       // (1-wx)*wy
            const float w00 = 1.0f - swx - swy + w11;

            f32x4 res = v00 * w00;
            res += v01 * w01;
            res += v10 * w10;
            res += v11 * w11;
            if (!sval) res = (f32x4)0.0f;      // wave-uniform

            __builtin_nontemporal_store(res, &o4[(size_t)sox + lane]);
        }
    }
}

// ---- fallback for nbox > MAXB: two-kernel path (never taken here) ----------
__global__ __launch_bounds__(512) void bucket_kernel(
    const int* __restrict__ box_ind, int* __restrict__ order,
    int* __restrict__ offsets, int n)
{
    const int wave = threadIdx.x >> 6;
    const int lane = threadIdx.x & 63;
    __shared__ int counts[NIMG];
    int cnt = 0;
    for (int i = lane; i < n; i += 64) cnt += (box_ind[i] == wave);
    for (int off = 32; off; off >>= 1) cnt += __shfl_down(cnt, off);
    if (lane == 0) counts[wave] = cnt;
    __syncthreads();
    int start = 0;
    for (int i = 0; i < wave; ++i) start += counts[i];
    if (threadIdx.x == 0) {
        int acc = 0;
        for (int i = 0; i < NIMG; ++i) { offsets[i] = acc; acc += counts[i]; }
        offsets[NIMG] = acc;
    }
    int pos = start;
    for (int base = 0; base < n; base += 64) {
        const int i = base + lane;
        const bool m = (i < n) && (box_ind[i] == wave);
        const unsigned long long mask = __ballot(m);
        const int below = __popcll(mask & ((1ULL << lane) - 1ULL));
        if (m) order[pos + below] = i;
        pos += __popcll(mask);
    }
}

__global__ __launch_bounds__(256) void crop_global_order(
    const float* __restrict__ feats,
    const float* __restrict__ boxes,
    const int*   __restrict__ order,
    const int*   __restrict__ offsets,
    float*       __restrict__ out)
{
    const int img  = blockIdx.x & 7;
    const int slot = blockIdx.x >> 3;
    const int lane = threadIdx.x & 63;
    const int wv   = threadIdx.x >> 6;
    const int start   = offsets[img];
    const int nb      = offsets[img + 1] - start;
    const int ncells  = nb * CROP_HW;
    const int ngroups = (ncells + G - 1) / G;
    const int wave_local = slot * 4 + wv;
    const int stride     = (gridDim.x >> 3) * 4;
    const f32x4* __restrict__ f4 = reinterpret_cast<const f32x4*>(feats)
                                   + (size_t)img * (H * W * (C / 4));
    const f32x4* __restrict__ boxes4 = reinterpret_cast<const f32x4*>(boxes);
    f32x4* __restrict__ o4 = reinterpret_cast<f32x4*>(out);

    for (int gi = wave_local; gi < ngroups; gi += stride) {
        const int cbase = gi * G;
        const int nval  = min(G, ncells - cbase);
        int c = cbase + (lane & (G - 1));
        if (c > ncells - 1) c = ncells - 1;
        const Cell k = cell_info(c, order + start, boxes4);
        const unsigned long long vmask = __ballot(k.valid);
        #pragma unroll
        for (int j = 0; j < G; ++j) {
            if (j >= nval) break;
            const int   s00 = __builtin_amdgcn_readlane(k.p00, j);
            const int   s01 = __builtin_amdgcn_readlane(k.p01, j);
            const int   s10 = __builtin_amdgcn_readlane(k.p10, j);
            const int   s11 = __builtin_amdgcn_readlane(k.p11, j);
            const float swx = __uint_as_float(
                __builtin_amdgcn_readlane(__float_as_uint(k.wx), j));
            const float swy = __uint_as_float(
                __builtin_amdgcn_readlane(__float_as_uint(k.wy), j));
            const int   sox = __builtin_amdgcn_readlane(k.oidx, j);
            const bool  sval = (vmask >> j) & 1ULL;
            const f32x4 v00 = f4[s00 * (C / 4) + lane];
            const f32x4 v01 = f4[s01 * (C / 4) + lane];
            const f32x4 v10 = f4[s10 * (C / 4) + lane];
            const f32x4 v11 = f4[s11 * (C / 4) + lane];
            const float w11 = swx * swy;
            const float w01 = swx - w11;
            const float w10 = swy - w11;
            const float w00 = 1.0f - swx - swy + w11;
            f32x4 res = v00 * w00;
            res += v01 * w01;
            res += v10 * w10;
            res += v11 * w11;
            if (!sval) res = (f32x4)0.0f;
            __builtin_nontemporal_store(res, &o4[(size_t)sox + lane]);
        }
    }
}

extern "C" void kernel_launch(void* const* d_in, const int* in_sizes, int n_in,
                              void* d_out, int out_size, void* d_ws, size_t ws_size,
                              hipStream_t stream) {
    const float* feats   = (const float*)d_in[0];
    const float* boxes   = (const float*)d_in[1];
    const int*   box_ind = (const int*)d_in[2];
    float*       out     = (float*)d_out;

    const int n_boxes = in_sizes[1] / 4;

    if (n_boxes <= MAXB) {
        // single launch: in-LDS bucket + crop. 6144 blocks (768/image).
        crop_resize_xcd<<<6144, 256, 0, stream>>>(feats, boxes, box_ind, out,
                                                  n_boxes);
    } else {
        int* order   = (int*)d_ws;
        int* offsets = order + n_boxes;
        bucket_kernel<<<1, 512, 0, stream>>>(box_ind, order, offsets, n_boxes);
        crop_global_order<<<6144, 256, 0, stream>>>(feats, boxes, order,
                                                    offsets, out);
    }
}